// Round 1
// baseline (378.983 us; speedup 1.0000x reference)
//
#include <hip/hip_runtime.h>
#include <math.h>

// Problem constants (fixed by the reference setup_inputs)
constexpr int DIM    = 512;
constexpr int NTOK   = 16384;
constexpr int NBATCH = 8;
constexpr int CHUNK  = 64;               // tokens per wave-chunk
constexpr int CPB    = NTOK / CHUNK;     // 256 chunks per batch
constexpr int WPB    = 4;                // waves per block (256 threads)
constexpr int NCHUNKS = NBATCH * CPB;    // 2048 total chunks

// Stage 1: online-softmax partial reduction. One wave = one 64-token chunk.
// Lane i owns row elements [4i,4i+4) and [256+4i, 256+4i+4) -> two coalesced
// 1KiB float4 wave loads per token. Wave-uniform score via shfl_xor reduce.
__global__ __launch_bounds__(256, 2)
void ga_stage1(const float* __restrict__ x,
               const float* __restrict__ Wa, const float* __restrict__ ba,
               const float* __restrict__ Wg, const float* __restrict__ bg,
               float* __restrict__ wm, float* __restrict__ wl,
               float* __restrict__ wv)
{
    const int lane = threadIdx.x & 63;
    const int wave = threadIdx.x >> 6;
    const int gw   = blockIdx.x * WPB + wave;   // global chunk id, 0..2047
    const int b    = gw / CPB;
    const int c    = gw % CPB;

    const float4* xq = (const float4*)(x + ((size_t)b * NTOK + (size_t)c * CHUNK) * DIM);

    // weight fragments matching the lane->element mapping
    const float4 wa0 = ((const float4*)Wa)[lane];
    const float4 wa1 = ((const float4*)Wa)[64 + lane];
    const float4 wg0 = ((const float4*)Wg)[lane];
    const float4 wg1 = ((const float4*)Wg)[64 + lane];
    const float bav = ba[0], bgv = bg[0];

    float m = -INFINITY, l = 0.0f;
    float a0x=0.f,a0y=0.f,a0z=0.f,a0w=0.f;
    float a1x=0.f,a1y=0.f,a1z=0.f,a1w=0.f;

    constexpr int U = 4;               // tokens per group (prefetch depth)
    constexpr int G = CHUNK / U;

    float4 b0[U], b1[U];
    #pragma unroll
    for (int u = 0; u < U; ++u) {
        b0[u] = xq[u * 128 + lane];        // token u, first 256 floats
        b1[u] = xq[u * 128 + 64 + lane];   // token u, second 256 floats
    }

    for (int g = 0; g < G; ++g) {
        float4 n0[U], n1[U];
        if (g + 1 < G) {
            const float4* nq = xq + (size_t)(g + 1) * U * 128;
            #pragma unroll
            for (int u = 0; u < U; ++u) {
                n0[u] = nq[u * 128 + lane];
                n1[u] = nq[u * 128 + 64 + lane];
            }
        }
        #pragma unroll
        for (int u = 0; u < U; ++u) {
            float da = b0[u].x*wa0.x + b0[u].y*wa0.y + b0[u].z*wa0.z + b0[u].w*wa0.w
                     + b1[u].x*wa1.x + b1[u].y*wa1.y + b1[u].z*wa1.z + b1[u].w*wa1.w;
            float dg = b0[u].x*wg0.x + b0[u].y*wg0.y + b0[u].z*wg0.z + b0[u].w*wg0.w
                     + b1[u].x*wg1.x + b1[u].y*wg1.y + b1[u].z*wg1.z + b1[u].w*wg1.w;
            #pragma unroll
            for (int off = 32; off > 0; off >>= 1) {
                da += __shfl_xor(da, off, 64);
                dg += __shfl_xor(dg, off, 64);
            }
            const float za = da + bav;
            const float zg = dg + bgv;
            const float s  = tanhf(za) / (1.0f + expf(-zg));   // tanh * sigmoid
            const float mn   = fmaxf(m, s);
            const float corr = expf(m - mn);   // m starts -inf -> corr=0 first token
            const float p    = expf(s - mn);
            l = l * corr + p;
            a0x = a0x*corr + p*b0[u].x;  a0y = a0y*corr + p*b0[u].y;
            a0z = a0z*corr + p*b0[u].z;  a0w = a0w*corr + p*b0[u].w;
            a1x = a1x*corr + p*b1[u].x;  a1y = a1y*corr + p*b1[u].y;
            a1z = a1z*corr + p*b1[u].z;  a1w = a1w*corr + p*b1[u].w;
            m = mn;
        }
        if (g + 1 < G) {
            #pragma unroll
            for (int u = 0; u < U; ++u) { b0[u] = n0[u]; b1[u] = n1[u]; }
        }
    }

    if (lane == 0) { wm[gw] = m; wl[gw] = l; }
    float4* vq = (float4*)(wv + (size_t)gw * DIM);
    vq[lane]      = make_float4(a0x, a0y, a0z, a0w);
    vq[64 + lane] = make_float4(a1x, a1y, a1z, a1w);
}

// Stage 2: combine 256 chunk-partials per batch. One block per batch.
__global__ __launch_bounds__(256)
void ga_stage2(const float* __restrict__ wm, const float* __restrict__ wl,
               const float* __restrict__ wv, float* __restrict__ out)
{
    const int b   = blockIdx.x;
    const int tid = threadIdx.x;           // 256 == CPB
    __shared__ float sa[CPB];
    __shared__ float red[256];

    const int cid = b * CPB + tid;
    const float mc = wm[cid];
    const float lc = wl[cid];

    // global max over chunk maxima
    red[tid] = mc;
    __syncthreads();
    for (int s = 128; s > 0; s >>= 1) {
        if (tid < s) red[tid] = fmaxf(red[tid], red[tid + s]);
        __syncthreads();
    }
    const float M = red[0];
    __syncthreads();

    // rescale factors and total denominator
    const float alpha = expf(mc - M);
    sa[tid]  = alpha;
    red[tid] = alpha * lc;
    __syncthreads();
    for (int s = 128; s > 0; s >>= 1) {
        if (tid < s) red[tid] += red[tid + s];
        __syncthreads();
    }
    const float L = red[0];

    // combine partial vectors: element tid and tid+256
    const float* vb = wv + (size_t)b * CPB * DIM;
    float acc0 = 0.0f, acc1 = 0.0f;
    for (int c = 0; c < CPB; ++c) {
        const float al = sa[c];
        acc0 += al * vb[(size_t)c * DIM + tid];
        acc1 += al * vb[(size_t)c * DIM + 256 + tid];
    }
    const float invL = 1.0f / L;
    out[(size_t)b * DIM + tid]       = acc0 * invL;
    out[(size_t)b * DIM + 256 + tid] = acc1 * invL;
}

extern "C" void kernel_launch(void* const* d_in, const int* in_sizes, int n_in,
                              void* d_out, int out_size, void* d_ws, size_t ws_size,
                              hipStream_t stream)
{
    const float* x  = (const float*)d_in[0];
    const float* Wa = (const float*)d_in[1];
    const float* ba = (const float*)d_in[2];
    const float* Wg = (const float*)d_in[3];
    const float* bg = (const float*)d_in[4];
    float* out = (float*)d_out;

    // workspace layout: m[2048] | l[2048] | v[2048*512]  (~4.02 MiB)
    float* wm = (float*)d_ws;
    float* wl = wm + NCHUNKS;
    float* wv = wl + NCHUNKS;

    ga_stage1<<<NCHUNKS / WPB, 256, 0, stream>>>(x, Wa, ba, Wg, bg, wm, wl, wv);
    ga_stage2<<<NBATCH, 256, 0, stream>>>(wm, wl, wv, out);
}

// Round 2
// 372.486 us; speedup vs baseline: 1.0174x; 1.0174x over previous
//
#include <hip/hip_runtime.h>
#include <math.h>

// Problem constants (fixed by the reference setup_inputs)
constexpr int DIM    = 512;
constexpr int NTOK   = 16384;
constexpr int NBATCH = 8;
constexpr int CHUNK  = 32;               // tokens per wave-chunk
constexpr int CPB    = NTOK / CHUNK;     // 512 chunks per batch
constexpr int WPB    = 4;                // waves per block (256 threads)
constexpr int NCHUNKS = NBATCH * CPB;    // 4096 total chunks
constexpr int S2_CHUNKS = 32;            // chunks reduced per stage2 block
constexpr int S2_BLOCKS_PER_B = CPB / S2_CHUNKS;  // 16
constexpr int S2_BLOCKS = NBATCH * S2_BLOCKS_PER_B; // 128

// Scores s = tanh(za)*sigmoid(zg) are bounded in (-1,1), so softmax needs no
// max subtraction: p = exp(s) can't overflow and sum over 16384 tokens stays
// ~O(4e4). This removes the serial online-max chain entirely.

// Stage 1: one wave = one 32-token chunk. Lane i owns row elements [4i,4i+4)
// and [256+4i,256+4i+4) -> two coalesced 1KiB float4 wave loads per token.
__global__ __launch_bounds__(256, 4)
void ga_stage1(const float* __restrict__ x,
               const float* __restrict__ Wa, const float* __restrict__ ba,
               const float* __restrict__ Wg, const float* __restrict__ bg,
               float* __restrict__ wl, float* __restrict__ wv)
{
    const int lane = threadIdx.x & 63;
    const int wave = threadIdx.x >> 6;
    const int gw   = blockIdx.x * WPB + wave;   // global chunk id, 0..4095
    const int b    = gw / CPB;
    const int c    = gw % CPB;

    const float4* xq = (const float4*)(x + ((size_t)b * NTOK + (size_t)c * CHUNK) * DIM);

    const float4 wa0 = ((const float4*)Wa)[lane];
    const float4 wa1 = ((const float4*)Wa)[64 + lane];
    const float4 wg0 = ((const float4*)Wg)[lane];
    const float4 wg1 = ((const float4*)Wg)[64 + lane];
    const float bav = ba[0], bgv = bg[0];

    float l = 0.0f;
    float a0x=0.f,a0y=0.f,a0z=0.f,a0w=0.f;
    float a1x=0.f,a1y=0.f,a1z=0.f,a1w=0.f;

    constexpr int U = 4;               // tokens per group (prefetch depth)
    constexpr int G = CHUNK / U;       // 8 groups

    float4 b0[U], b1[U];
    #pragma unroll
    for (int u = 0; u < U; ++u) {
        b0[u] = xq[u * 128 + lane];        // token u, first 256 floats
        b1[u] = xq[u * 128 + 64 + lane];   // token u, second 256 floats
    }

    for (int g = 0; g < G; ++g) {
        float4 n0[U], n1[U];
        if (g + 1 < G) {
            const float4* nq = xq + (size_t)(g + 1) * U * 128;
            #pragma unroll
            for (int u = 0; u < U; ++u) {
                n0[u] = nq[u * 128 + lane];
                n1[u] = nq[u * 128 + 64 + lane];
            }
        }
        #pragma unroll
        for (int u = 0; u < U; ++u) {
            float da = b0[u].x*wa0.x + b0[u].y*wa0.y + b0[u].z*wa0.z + b0[u].w*wa0.w
                     + b1[u].x*wa1.x + b1[u].y*wa1.y + b1[u].z*wa1.z + b1[u].w*wa1.w;
            float dg = b0[u].x*wg0.x + b0[u].y*wg0.y + b0[u].z*wg0.z + b0[u].w*wg0.w
                     + b1[u].x*wg1.x + b1[u].y*wg1.y + b1[u].z*wg1.z + b1[u].w*wg1.w;
            #pragma unroll
            for (int off = 32; off > 0; off >>= 1) {
                da += __shfl_xor(da, off, 64);
                dg += __shfl_xor(dg, off, 64);
            }
            const float s = tanhf(da + bav) / (1.0f + expf(-(dg + bgv)));
            const float p = expf(s);           // s in (-1,1): no max needed
            l += p;
            a0x += p*b0[u].x;  a0y += p*b0[u].y;
            a0z += p*b0[u].z;  a0w += p*b0[u].w;
            a1x += p*b1[u].x;  a1y += p*b1[u].y;
            a1z += p*b1[u].z;  a1w += p*b1[u].w;
        }
        if (g + 1 < G) {
            #pragma unroll
            for (int u = 0; u < U; ++u) { b0[u] = n0[u]; b1[u] = n1[u]; }
        }
    }

    if (lane == 0) wl[gw] = l;
    float4* vq = (float4*)(wv + (size_t)gw * DIM);
    vq[lane]      = make_float4(a0x, a0y, a0z, a0w);
    vq[64 + lane] = make_float4(a1x, a1y, a1z, a1w);
}

// Stage 2: tree level 1 — each block reduces 32 chunk-partials.
__global__ __launch_bounds__(256)
void ga_stage2(const float* __restrict__ wl, const float* __restrict__ wv,
               float* __restrict__ l2, float* __restrict__ v2)
{
    const int bb  = blockIdx.x;            // 0..127: (batch, j)
    const int tid = threadIdx.x;
    const int cid0 = bb * S2_CHUNKS;       // chunks are batch-contiguous

    float acc0 = 0.0f, acc1 = 0.0f;
    const float* vb = wv + (size_t)cid0 * DIM;
    #pragma unroll 4
    for (int c = 0; c < S2_CHUNKS; ++c) {
        acc0 += vb[(size_t)c * DIM + tid];
        acc1 += vb[(size_t)c * DIM + 256 + tid];
    }
    v2[(size_t)bb * DIM + tid]       = acc0;
    v2[(size_t)bb * DIM + 256 + tid] = acc1;

    // l reduction: wave 0, lanes 0..31 hold one value each
    if (tid < 64) {
        float lv = (tid < S2_CHUNKS) ? wl[cid0 + tid] : 0.0f;
        #pragma unroll
        for (int off = 32; off > 0; off >>= 1) lv += __shfl_xor(lv, off, 64);
        if (tid == 0) l2[bb] = lv;
    }
}

// Stage 3: tree level 2 — combine 16 partials per batch, divide by L.
__global__ __launch_bounds__(256)
void ga_stage3(const float* __restrict__ l2, const float* __restrict__ v2,
               float* __restrict__ out)
{
    const int b   = blockIdx.x;
    const int tid = threadIdx.x;

    float L = 0.0f;
    #pragma unroll
    for (int j = 0; j < S2_BLOCKS_PER_B; ++j) L += l2[b * S2_BLOCKS_PER_B + j];

    float a0 = 0.0f, a1 = 0.0f;
    const float* vb = v2 + (size_t)b * S2_BLOCKS_PER_B * DIM;
    #pragma unroll
    for (int j = 0; j < S2_BLOCKS_PER_B; ++j) {
        a0 += vb[(size_t)j * DIM + tid];
        a1 += vb[(size_t)j * DIM + 256 + tid];
    }
    const float invL = 1.0f / L;
    out[(size_t)b * DIM + tid]       = a0 * invL;
    out[(size_t)b * DIM + 256 + tid] = a1 * invL;
}

extern "C" void kernel_launch(void* const* d_in, const int* in_sizes, int n_in,
                              void* d_out, int out_size, void* d_ws, size_t ws_size,
                              hipStream_t stream)
{
    const float* x  = (const float*)d_in[0];
    const float* Wa = (const float*)d_in[1];
    const float* ba = (const float*)d_in[2];
    const float* Wg = (const float*)d_in[3];
    const float* bg = (const float*)d_in[4];
    float* out = (float*)d_out;

    // ws layout: wl[4096] | wv[4096*512] | l2[128] | v2[128*512]  (~8.7 MiB)
    float* wl = (float*)d_ws;
    float* wv = wl + NCHUNKS;
    float* l2 = wv + (size_t)NCHUNKS * DIM;
    float* v2 = l2 + S2_BLOCKS;

    ga_stage1<<<NCHUNKS / WPB, 256, 0, stream>>>(x, Wa, ba, Wg, bg, wl, wv);
    ga_stage2<<<S2_BLOCKS, 256, 0, stream>>>(wl, wv, l2, v2);
    ga_stage3<<<NBATCH, 256, 0, stream>>>(l2, v2, out);
}

// Round 3
// 372.470 us; speedup vs baseline: 1.0175x; 1.0000x over previous
//
#include <hip/hip_runtime.h>
#include <math.h>

// Problem constants (fixed by the reference setup_inputs)
constexpr int DIM    = 512;
constexpr int NTOK   = 16384;
constexpr int NBATCH = 8;
constexpr int CHUNK  = 64;               // tokens per wave-chunk
constexpr int CPB    = NTOK / CHUNK;     // 256 chunks per batch
constexpr int WPB    = 4;                // waves per block (256 threads)
constexpr int NCHUNKS = NBATCH * CPB;    // 2048 total chunks
constexpr int S2_CHUNKS = 32;            // chunks reduced per stage2 block
constexpr int S2_BLOCKS_PER_B = CPB / S2_CHUNKS;    // 8
constexpr int S2_BLOCKS = NBATCH * S2_BLOCKS_PER_B; // 64

// Scores s = tanh(za)*sigmoid(zg) are bounded in (-1,1): softmax needs no
// max subtraction (exp(s) can't overflow; sum over 16384 tokens ~4e4).

// Stage 1: one wave = one 64-token chunk. Lane i owns row elements [4i,4i+4)
// and [256+4i,256+4i+4) -> two coalesced 1KiB float4 wave loads per token.
// Packed dual butterfly: reduce da and dg together in 8 shuffles instead of 12
// (offsets 2..32 preserve lane parity, so even lanes carry the da tree and odd
// lanes the dg tree after one pre-step).
__global__ __launch_bounds__(256, 2)
void ga_stage1(const float* __restrict__ x,
               const float* __restrict__ Wa, const float* __restrict__ ba,
               const float* __restrict__ Wg, const float* __restrict__ bg,
               float* __restrict__ wl, float* __restrict__ wv)
{
    const int lane = threadIdx.x & 63;
    const int wave = threadIdx.x >> 6;
    const int gw   = blockIdx.x * WPB + wave;   // global chunk id, 0..2047
    const int b    = gw / CPB;
    const int c    = gw % CPB;
    const bool even = (lane & 1) == 0;

    const float4* xq = (const float4*)(x + ((size_t)b * NTOK + (size_t)c * CHUNK) * DIM);

    const float4 wa0 = ((const float4*)Wa)[lane];
    const float4 wa1 = ((const float4*)Wa)[64 + lane];
    const float4 wg0 = ((const float4*)Wg)[lane];
    const float4 wg1 = ((const float4*)Wg)[64 + lane];
    const float bav = ba[0], bgv = bg[0];

    float l = 0.0f;
    float a0x=0.f,a0y=0.f,a0z=0.f,a0w=0.f;
    float a1x=0.f,a1y=0.f,a1z=0.f,a1w=0.f;

    constexpr int U = 4;               // tokens per group (prefetch depth)
    constexpr int G = CHUNK / U;       // 16 groups

    float4 b0[U], b1[U];
    #pragma unroll
    for (int u = 0; u < U; ++u) {
        b0[u] = xq[u * 128 + lane];        // token u, first 256 floats
        b1[u] = xq[u * 128 + 64 + lane];   // token u, second 256 floats
    }

    for (int g = 0; g < G; ++g) {
        float4 n0[U], n1[U];
        if (g + 1 < G) {
            const float4* nq = xq + (size_t)(g + 1) * U * 128;
            #pragma unroll
            for (int u = 0; u < U; ++u) {
                n0[u] = nq[u * 128 + lane];
                n1[u] = nq[u * 128 + 64 + lane];
            }
        }
        #pragma unroll
        for (int u = 0; u < U; ++u) {
            float da = b0[u].x*wa0.x + b0[u].y*wa0.y + b0[u].z*wa0.z + b0[u].w*wa0.w
                     + b1[u].x*wa1.x + b1[u].y*wa1.y + b1[u].z*wa1.z + b1[u].w*wa1.w;
            float dg = b0[u].x*wg0.x + b0[u].y*wg0.y + b0[u].z*wg0.z + b0[u].w*wg0.w
                     + b1[u].x*wg1.x + b1[u].y*wg1.y + b1[u].z*wg1.z + b1[u].w*wg1.w;
            // packed dual 64-lane reduction (8 shuffles total)
            float ta = da + __shfl_xor(da, 1, 64);      // pair sums
            float tg = dg + __shfl_xor(dg, 1, 64);
            float v  = even ? ta : tg;                  // even->da tree, odd->dg tree
            #pragma unroll
            for (int off = 2; off <= 32; off <<= 1)
                v += __shfl_xor(v, off, 64);
            const float u2 = __shfl_xor(v, 1, 64);      // cross-parity swap
            const float daf = even ? v : u2;
            const float dgf = even ? u2 : v;

            const float s = tanhf(daf + bav) / (1.0f + expf(-(dgf + bgv)));
            const float p = expf(s);                     // s in (-1,1): no max
            l += p;
            a0x += p*b0[u].x;  a0y += p*b0[u].y;
            a0z += p*b0[u].z;  a0w += p*b0[u].w;
            a1x += p*b1[u].x;  a1y += p*b1[u].y;
            a1z += p*b1[u].z;  a1w += p*b1[u].w;
        }
        if (g + 1 < G) {
            #pragma unroll
            for (int u = 0; u < U; ++u) { b0[u] = n0[u]; b1[u] = n1[u]; }
        }
    }

    if (lane == 0) wl[gw] = l;
    float4* vq = (float4*)(wv + (size_t)gw * DIM);
    vq[lane]      = make_float4(a0x, a0y, a0z, a0w);
    vq[64 + lane] = make_float4(a1x, a1y, a1z, a1w);
}

// Stage 2: tree level 1 — each block reduces 32 chunk-partials.
__global__ __launch_bounds__(256)
void ga_stage2(const float* __restrict__ wl, const float* __restrict__ wv,
               float* __restrict__ l2, float* __restrict__ v2)
{
    const int bb  = blockIdx.x;            // 0..63: (batch, j)
    const int tid = threadIdx.x;
    const int cid0 = bb * S2_CHUNKS;       // chunks are batch-contiguous

    float acc0 = 0.0f, acc1 = 0.0f;
    const float* vb = wv + (size_t)cid0 * DIM;
    #pragma unroll 4
    for (int c = 0; c < S2_CHUNKS; ++c) {
        acc0 += vb[(size_t)c * DIM + tid];
        acc1 += vb[(size_t)c * DIM + 256 + tid];
    }
    v2[(size_t)bb * DIM + tid]       = acc0;
    v2[(size_t)bb * DIM + 256 + tid] = acc1;

    if (tid < 64) {
        float lv = (tid < S2_CHUNKS) ? wl[cid0 + tid] : 0.0f;
        #pragma unroll
        for (int off = 32; off > 0; off >>= 1) lv += __shfl_xor(lv, off, 64);
        if (tid == 0) l2[bb] = lv;
    }
}

// Stage 3: tree level 2 — combine 8 partials per batch, divide by L.
__global__ __launch_bounds__(256)
void ga_stage3(const float* __restrict__ l2, const float* __restrict__ v2,
               float* __restrict__ out)
{
    const int b   = blockIdx.x;
    const int tid = threadIdx.x;

    float L = 0.0f;
    #pragma unroll
    for (int j = 0; j < S2_BLOCKS_PER_B; ++j) L += l2[b * S2_BLOCKS_PER_B + j];

    float a0 = 0.0f, a1 = 0.0f;
    const float* vb = v2 + (size_t)b * S2_BLOCKS_PER_B * DIM;
    #pragma unroll
    for (int j = 0; j < S2_BLOCKS_PER_B; ++j) {
        a0 += vb[(size_t)j * DIM + tid];
        a1 += vb[(size_t)j * DIM + 256 + tid];
    }
    const float invL = 1.0f / L;
    out[(size_t)b * DIM + tid]       = a0 * invL;
    out[(size_t)b * DIM + 256 + tid] = a1 * invL;
}

extern "C" void kernel_launch(void* const* d_in, const int* in_sizes, int n_in,
                              void* d_out, int out_size, void* d_ws, size_t ws_size,
                              hipStream_t stream)
{
    const float* x  = (const float*)d_in[0];
    const float* Wa = (const float*)d_in[1];
    const float* ba = (const float*)d_in[2];
    const float* Wg = (const float*)d_in[3];
    const float* bg = (const float*)d_in[4];
    float* out = (float*)d_out;

    // ws layout: wl[2048] | wv[2048*512] | l2[64] | v2[64*512]  (~4.3 MiB)
    float* wl = (float*)d_ws;
    float* wv = wl + NCHUNKS;
    float* l2 = wv + (size_t)NCHUNKS * DIM;
    float* v2 = l2 + S2_BLOCKS;

    ga_stage1<<<NCHUNKS / WPB, 256, 0, stream>>>(x, Wa, ba, Wg, bg, wl, wv);
    ga_stage2<<<S2_BLOCKS, 256, 0, stream>>>(wl, wv, l2, v2);
    ga_stage3<<<NBATCH, 256, 0, stream>>>(l2, v2, out);
}